// Round 4
// baseline (505.840 us; speedup 1.0000x reference)
//
#include <hip/hip_runtime.h>
#include <cstdint>
#include <cstddef>

typedef __bf16 bf16;
typedef __bf16 bf16x8 __attribute__((ext_vector_type(8)));
typedef __bf16 bf16x4 __attribute__((ext_vector_type(4)));
typedef float  floatx4 __attribute__((ext_vector_type(4)));

#define MFMA16(a,b,c) __builtin_amdgcn_mfma_f32_16x16x32_bf16((a),(b),(c),0,0,0)

__device__ __forceinline__ void async_copy16(void* lds, const void* g) {
    __builtin_amdgcn_global_load_lds(
        (const __attribute__((address_space(1))) unsigned int*)g,
        (__attribute__((address_space(3))) unsigned int*)lds,
        16, 0, 0);
}

// ---------------- fused fp32 -> bf16 convert for all 4 weights ----------------
__global__ __launch_bounds__(256) void cvt_all(const float* __restrict__ s0,
                                               const float* __restrict__ s1,
                                               const float* __restrict__ s2,
                                               const float* __restrict__ s3,
                                               bf16* __restrict__ d0,
                                               bf16* __restrict__ d1,
                                               bf16* __restrict__ d2,
                                               bf16* __restrict__ d3) {
    const int blk = blockIdx.x;
    const float* src; bf16* dst; int base;
    if (blk < 3072)      { src = s0; dst = d0; base = blk; }
    else if (blk < 4096) { src = s1; dst = d1; base = blk - 3072; }
    else if (blk < 8192) { src = s2; dst = d2; base = blk - 4096; }
    else                 { src = s3; dst = d3; base = blk - 8192; }
    const int i = base * 256 + threadIdx.x;
    const float4 v = ((const float4*)src)[i];
    bf16x4 o;
    o[0] = (bf16)v.x; o[1] = (bf16)v.y; o[2] = (bf16)v.z; o[3] = (bf16)v.w;
    ((bf16x4*)dst)[i] = o;
}

// ---------------- LayerNorm (fp32 in, bf16 out), row = 1024 ----------------
__global__ __launch_bounds__(256) void ln_kernel(const float* __restrict__ x,
                                                 const float* __restrict__ w,
                                                 const float* __restrict__ b,
                                                 bf16* __restrict__ out) {
    const int row = blockIdx.x;
    const int t = threadIdx.x;
    const float4 v = ((const float4*)(x + (size_t)row * 1024))[t];
    float s  = v.x + v.y + v.z + v.w;
    float ss = v.x*v.x + v.y*v.y + v.z*v.z + v.w*v.w;
#pragma unroll
    for (int m = 32; m >= 1; m >>= 1) {
        s  += __shfl_xor(s,  m, 64);
        ss += __shfl_xor(ss, m, 64);
    }
    __shared__ float red[8];
    const int wave = t >> 6, lane = t & 63;
    if (lane == 0) { red[wave] = s; red[4 + wave] = ss; }
    __syncthreads();
    s  = red[0] + red[1] + red[2] + red[3];
    ss = red[4] + red[5] + red[6] + red[7];
    const float mean = s * (1.0f / 1024.0f);
    const float var  = ss * (1.0f / 1024.0f) - mean * mean;
    const float inv  = rsqrtf(var + 1e-6f);
    const float4 wv = ((const float4*)w)[t];
    const float4 bv = ((const float4*)b)[t];
    bf16x4 o;
    o[0] = (bf16)((v.x - mean) * inv * wv.x + bv.x);
    o[1] = (bf16)((v.y - mean) * inv * wv.y + bv.y);
    o[2] = (bf16)((v.z - mean) * inv * wv.z + bv.z);
    o[3] = (bf16)((v.w - mean) * inv * wv.w + bv.w);
    *(bf16x4*)(out + (size_t)row * 1024 + t * 4) = o;
}

// ---------------- BT-GEMM: C[M,N] = A[M,K] @ B[N,K]^T (+epilogue) ----------
// BK=64, XOR-swizzled LDS. MSTRIP: grid (8, mt_per*nt); XCD bx owns an
// m-strip (A-locality for small-N GEMMs). NSTRIP: XCD owns an n-slice.
template <int EPI, bool MSTRIP>
__global__ __launch_bounds__(256, 3) void gemm_bt(
    const bf16* __restrict__ A, const bf16* __restrict__ B,
    const float* __restrict__ bias, void* __restrict__ Cout,
    const float* __restrict__ res, const float* __restrict__ lsv,
    int M, int N, int K, int mt_per) {
    __shared__ bf16 sA[128 * 64];
    __shared__ bf16 sB[128 * 64];
    const int tid  = threadIdx.x;
    const int wave = tid >> 6;
    const int lane = tid & 63;
    const int lrow = lane & 15;
    const int quad = lane >> 4;
    int m0, n0;
    if constexpr (MSTRIP) {
        const int mtile = blockIdx.x * mt_per + blockIdx.y % mt_per;
        const int ntile = blockIdx.y / mt_per;
        m0 = mtile * 128;
        n0 = ntile * 128;
        if (m0 >= M) return;
    } else {
        const int nx   = gridDim.x;
        const int lin  = blockIdx.y * nx + blockIdx.x;
        const int w    = nx >> 3;
        const int xcd  = lin & 7;
        const int slot = lin >> 3;
        const int ntile = xcd * w + (slot % w);
        const int mtile = slot / w;
        m0 = mtile * 128;
        n0 = ntile * 128;
    }
    const int wm = (wave >> 1) * 64;
    const int wn = (wave & 1) * 64;

    floatx4 acc[4][4] = {};

    const int srow  = tid >> 3;                  // 0..31
    const int spart = (tid & 7) ^ (srow & 7);    // XOR-swizzled 16B-part
    const bf16* Ag[4];
    const bf16* Bg[4];
#pragma unroll
    for (int c = 0; c < 4; c++) {
        int am = m0 + c * 32 + srow; if (am > M - 1) am = M - 1;
        Ag[c] = A + (size_t)am * K + spart * 8;
        Bg[c] = B + (size_t)(n0 + c * 32 + srow) * K + spart * 8;
    }
    const int sswz = lrow & 7;

    for (int kk = 0; kk < K; kk += 64) {
        __syncthreads();
#pragma unroll
        for (int c = 0; c < 4; c++) {
            async_copy16(&sA[(c * 256 + wave * 64) * 8], Ag[c] + kk);
            async_copy16(&sB[(c * 256 + wave * 64) * 8], Bg[c] + kk);
        }
        __syncthreads();
#pragma unroll
        for (int kq = 0; kq < 2; kq++) {
            const int so = ((kq * 4 + quad) ^ sswz) * 8;
            bf16x8 af[4], bfr[4];
#pragma unroll
            for (int i = 0; i < 4; i++)
                af[i] = *(const bf16x8*)&sA[(wm + i * 16 + lrow) * 64 + so];
#pragma unroll
            for (int j = 0; j < 4; j++)
                bfr[j] = *(const bf16x8*)&sB[(wn + j * 16 + lrow) * 64 + so];
#pragma unroll
            for (int i = 0; i < 4; i++)
#pragma unroll
                for (int j = 0; j < 4; j++)
                    acc[i][j] = MFMA16(af[i], bfr[j], acc[i][j]);
        }
    }

    const int nb = n0 + wn + lrow;
#pragma unroll
    for (int i = 0; i < 4; i++) {
        const int mb = m0 + wm + i * 16 + quad * 4;
#pragma unroll
        for (int r = 0; r < 4; r++) {
            const int m = mb + r;
            if (m < M) {
#pragma unroll
                for (int j = 0; j < 4; j++) {
                    const int n = nb + j * 16;
                    float v = acc[i][j][r] + bias[n];
                    if constexpr (EPI == 0) {
                        ((bf16*)Cout)[(size_t)m * N + n] = (bf16)v;
                    } else if constexpr (EPI == 2) {
                        // fast tanh-GELU
                        const float s_ = v * (0.7978845608f + 0.0356774081f * v * v);
                        const float e2s = __builtin_amdgcn_exp2f(2.8853900817779268f * s_);
                        const float g = v * (1.0f - __builtin_amdgcn_rcpf(1.0f + e2s));
                        ((bf16*)Cout)[(size_t)m * N + n] = (bf16)g;
                    } else {
                        ((float*)Cout)[(size_t)m * N + n] =
                            res[(size_t)m * N + n] + lsv[n] * v;
                    }
                }
            }
        }
    }
}

// ---------------- V transpose: qkv[tok][2048+h*64+d] -> vt[(bh*64+d)][1152] --
__global__ __launch_bounds__(256) void transpose_v(const bf16* __restrict__ qkv,
                                                   bf16* __restrict__ vt) {
    const int tt = blockIdx.x;   // token tile (64 toks), 0..16
    const int bh = blockIdx.y;   // 0..127
    const int b = bh >> 4, h = bh & 15;
    __shared__ bf16 tile[64][72];
    const int t = threadIdx.x;
    const int tok0 = tt * 64;
#pragma unroll
    for (int i = 0; i < 4; i++) {
        const int idx4 = i * 256 + t;      // 0..1023
        const int tl = idx4 >> 4;          // 0..63
        const int d4 = (idx4 & 15) * 4;
        const int tok = tok0 + tl;
        bf16x4 val;
        val[0] = (bf16)0.0f; val[1] = (bf16)0.0f; val[2] = (bf16)0.0f; val[3] = (bf16)0.0f;
        if (tok <= 1024) {
            val = *(const bf16x4*)(qkv + ((size_t)(b * 1025 + tok)) * 3072 + 2048 + h * 64 + d4);
        }
        tile[d4 + 0][tl] = val[0];
        tile[d4 + 1][tl] = val[1];
        tile[d4 + 2][tl] = val[2];
        tile[d4 + 3][tl] = val[3];
    }
    __syncthreads();
#pragma unroll
    for (int i = 0; i < 4; i++) {
        const int idx4 = i * 256 + t;
        const int d = idx4 >> 4;
        const int t4 = (idx4 & 15) * 4;
        bf16x4 o;
        o[0] = tile[d][t4 + 0]; o[1] = tile[d][t4 + 1];
        o[2] = tile[d][t4 + 2]; o[3] = tile[d][t4 + 3];
        *(bf16x4*)(vt + ((size_t)bh * 64 + d) * 1152 + tok0 + t4) = o;
    }
}

// ---------------- flash attention (no-max softmax, S^T layout, KT=64) --------
// grid: (17 q-tiles of 64, 128 bh). LDS 25.6 KB -> 5-6 blocks/CU for barrier hiding.
__global__ __launch_bounds__(256, 4) void attn_kernel(const bf16* __restrict__ qkv,
                                                      const bf16* __restrict__ vt,
                                                      bf16* __restrict__ o_out) {
    const int qt = blockIdx.x;
    const int bh = blockIdx.y;
    const int b = bh >> 4, h = bh & 15;
    __shared__ bf16 sK[2 * 64 * 32];    // [ks][tok64][32]  8192 B
    __shared__ bf16 sV[2 * 64 * 32];    // [kc][d64][32]    8192 B
    __shared__ bf16 sQP[4 * 16 * 72];   // union: Q staging (8192 B) / per-wave P (9216 B)
    const int tid = threadIdx.x, wave = tid >> 6, lane = tid & 63;
    const int lrow = lane & 15, quad = lane >> 4, lko = quad * 8;
    const float cexp = 0.18033688011112042f;   // 0.125 * log2(e)
    const size_t row0 = (size_t)b * 1025;

    // stage Q (64x64) as [ks][row][32] into sQP front
#pragma unroll
    for (int i = 0; i < 2; i++) {
        const int g = i * 256 + tid;
        const int ks = g >> 8, rr = (g >> 2) & 63, p = g & 3;
        int qrow = qt * 64 + rr; if (qrow > 1024) qrow = 1024;
        async_copy16(&sQP[(i * 256 + wave * 64) * 8],
                     qkv + (row0 + qrow) * 3072 + h * 64 + ks * 32 + p * 8);
    }
    __syncthreads();
    bf16x8 qf[2];
    qf[0] = *(const bf16x8*)&sQP[(wave * 16 + lrow) * 32 + lko];
    qf[1] = *(const bf16x8*)&sQP[2048 + (wave * 16 + lrow) * 32 + lko];
#pragma unroll
    for (int i = 0; i < 8; i++) {
        qf[0][i] = (bf16)((float)qf[0][i] * cexp);
        qf[1][i] = (bf16)((float)qf[1][i] * cexp);
    }
    bf16x8 ones;
#pragma unroll
    for (int i = 0; i < 8; i++) ones[i] = (bf16)1.0f;

    floatx4 o[4] = {};
    floatx4 ol = {};
    bf16* pw = &sQP[wave * (16 * 72)];

    for (int ktile = 0; ktile < 17; ++ktile) {
        const int kt0 = ktile * 64;
        __syncthreads();
        // stage K tile (64x64) as [ks][tok][32]
#pragma unroll
        for (int i = 0; i < 2; i++) {
            const int g = i * 256 + tid;
            const int ks = g >> 8, tok = (g >> 2) & 63, p = g & 3;
            int krow = kt0 + tok; if (krow > 1024) krow = 1024;
            async_copy16(&sK[(i * 256 + wave * 64) * 8],
                         qkv + (row0 + krow) * 3072 + 1024 + h * 64 + ks * 32 + p * 8);
        }
        // stage V^T tile (64d x 64kt) as [kc][d][32]
#pragma unroll
        for (int i = 0; i < 2; i++) {
            const int g = i * 256 + tid;
            const int kc = g >> 8, d = (g >> 2) & 63, p = g & 3;
            async_copy16(&sV[(i * 256 + wave * 64) * 8],
                         vt + ((size_t)bh * 64 + d) * 1152 + kt0 + kc * 32 + p * 8);
        }
        __syncthreads();

        const bool lastTile = (ktile == 16);
#pragma unroll
        for (int nt = 0; nt < 4; nt++) {
            bf16x8 k0 = *(const bf16x8*)&sK[(nt * 16 + lrow) * 32 + lko];
            bf16x8 k1 = *(const bf16x8*)&sK[2048 + (nt * 16 + lrow) * 32 + lko];
            floatx4 z = {};
            z = MFMA16(k0, qf[0], z);
            z = MFMA16(k1, qf[1], z);
            bf16x4 pb;
#pragma unroll
            for (int r = 0; r < 4; r++) {
                float p = __builtin_amdgcn_exp2f(z[r]);
                if (lastTile) {
                    const int ktok = kt0 + nt * 16 + quad * 4 + r;
                    p = (ktok <= 1024) ? p : 0.0f;
                }
                pb[r] = (bf16)p;
            }
            *(bf16x4*)&pw[lrow * 72 + nt * 16 + quad * 4] = pb;
        }
#pragma unroll
        for (int ks = 0; ks < 2; ks++) {
            bf16x8 pa = *(const bf16x8*)&pw[lrow * 72 + ks * 32 + lko];
#pragma unroll
            for (int j = 0; j < 4; j++) {
                bf16x8 vb = *(const bf16x8*)&sV[ks * 2048 + (j * 16 + lrow) * 32 + lko];
                o[j] = MFMA16(pa, vb, o[j]);
            }
            ol = MFMA16(pa, ones, ol);
        }
    }

#pragma unroll
    for (int r = 0; r < 4; r++) {
        const int q = qt * 64 + wave * 16 + quad * 4 + r;
        if (q <= 1024) {
            const float inv = 1.0f / ol[r];
            const size_t orow = (row0 + q) * 1024 + h * 64;
#pragma unroll
            for (int j = 0; j < 4; j++)
                o_out[orow + j * 16 + lrow] = (bf16)(o[j][r] * inv);
        }
    }
}

// ---------------- launch ----------------
extern "C" void kernel_launch(void* const* d_in, const int* in_sizes, int n_in,
                              void* d_out, int out_size, void* d_ws, size_t ws_size,
                              hipStream_t stream) {
    const float* x      = (const float*)d_in[0];
    const float* qkv_w  = (const float*)d_in[1];
    const float* qkv_b  = (const float*)d_in[2];
    const float* proj_w = (const float*)d_in[3];
    const float* proj_b = (const float*)d_in[4];
    const float* fc1_w  = (const float*)d_in[5];
    const float* fc1_b  = (const float*)d_in[6];
    const float* fc2_w  = (const float*)d_in[7];
    const float* fc2_b  = (const float*)d_in[8];
    const float* n1w    = (const float*)d_in[9];
    const float* n1b    = (const float*)d_in[10];
    const float* n2w    = (const float*)d_in[11];
    const float* n2b    = (const float*)d_in[12];
    const float* ls1    = (const float*)d_in[13];
    const float* ls2    = (const float*)d_in[14];

    char* ws = (char*)d_ws;
    bf16*  wqkv  = (bf16*)(ws + 0);            // 6291456
    bf16*  wproj = (bf16*)(ws + 6291456);      // 2097152
    bf16*  wfc1  = (bf16*)(ws + 8388608);      // 8388608
    bf16*  wfc2  = (bf16*)(ws + 16777216);     // 8388608
    bf16*  vt    = (bf16*)(ws + 25165824);     // 18874368
    bf16*  attnO = (bf16*)(ws + 44040192);     // 16793600
    float* x1    = (float*)(ws + 60833792);    // 33587200
    bf16*  lnbuf = (bf16*)(ws + 94420992);     // 16793600
    bf16*  big   = (bf16*)(ws + 111214592);    // qkv / h

    const int M = 8200;

    cvt_all<<<12288, 256, 0, stream>>>(qkv_w, proj_w, fc1_w, fc2_w,
                                       wqkv, wproj, wfc1, wfc2);

    ln_kernel<<<M, 256, 0, stream>>>(x, n1w, n1b, lnbuf);
    gemm_bt<0, false><<<dim3(24, 65), 256, 0, stream>>>(lnbuf, wqkv, qkv_b, (void*)big,
                                                        nullptr, nullptr, M, 3072, 1024, 0);
    transpose_v<<<dim3(17, 128), 256, 0, stream>>>(big, vt);
    attn_kernel<<<dim3(17, 128), 256, 0, stream>>>(big, vt, attnO);
    gemm_bt<1, true><<<dim3(8, 72), 256, 0, stream>>>(attnO, wproj, proj_b, (void*)x1,
                                                      x, ls1, M, 1024, 1024, 9);
    ln_kernel<<<M, 256, 0, stream>>>(x1, n2w, n2b, lnbuf);
    gemm_bt<2, false><<<dim3(32, 65), 256, 0, stream>>>(lnbuf, wfc1, fc1_b, (void*)big,
                                                        nullptr, nullptr, M, 4096, 1024, 0);
    gemm_bt<3, true><<<dim3(8, 72), 256, 0, stream>>>(big, wfc2, fc2_b, d_out,
                                                      x1, ls2, M, 1024, 4096, 9);
}